// Round 7
// baseline (61.777 us; speedup 1.0000x reference)
//
#include <hip/hip_runtime.h>

#define E_N 65536
#define T_N 9

typedef __bf16 bf16x8 __attribute__((ext_vector_type(8)));
typedef float f32x4 __attribute__((ext_vector_type(4)));
typedef unsigned short ushort8 __attribute__((ext_vector_type(8)));
union U8 { ushort8 u; bf16x8 b; };
union BF2 { __bf16 h[2]; unsigned int u; };

// ---------------- ws layout (float offsets) ----------------
#define OFF_CB   0          // 9*256*256 ushort = 294912 floats (bf16 packed C)
#define OFF_ABC  294912     // 56*256 floats
#define OFF_D2   309248     // 9*256 floats
#define OFF_CNT  311552     // 9 counters padded to 16 ints (1 cacheline) each
#define OFF_IDX  311712     // 9*65536 ints
#define WS_NEED_BYTES ((size_t)(311712 + 589824) * 4)

__device__ __constant__ float SCALES_C[9][4] = {
  {1.f,    1e-6f, 1.f,  1.f},
  {1.f,    1e-6f, 1.f,  1.f},
  {1.f,    1.f,   1.f,  1.f},
  {1e3f,   1.f,   1.f,  1.f},
  {1e-12f, 1.f,   1.f,  1.f},
  {1e-9f,  1.f,   1.f,  1.f},
  {1.f,    1.f,   1.f,  1.f},
  {1e-3f,  1e-3f, 1.f,  1.f},
  {1.f,    1.f,   1e9f, 1.f},
};

__device__ inline unsigned short f2bf(float f) {
  unsigned int u = __float_as_uint(f);
  unsigned int r = (u + 0x7FFFu + ((u >> 16) & 1u)) >> 16;
  return (unsigned short)r;
}

// ============ K1: fused independent prep ============
// blocks [0,256): scatter (block-aggregated atomics, line-padded counters)
// blocks [256,321): embed/bias projections (k-split across waves + LDS reduce)
// blocks [321,609): C[t] = W2[t]@Wf2 (per-wave k-quarter, conflict-free partials)
struct ScatSM { int sph[9][4]; int sbase[9]; };
struct EmbSM  { float partf[4 * 64 * 4]; };
struct CSM    { float w2s[8][256]; float partf[3 * 8 * 64 * 4]; };
union PrepSM  { ScatSM s; EmbSM e; CSM c; };

__global__ __launch_bounds__(256) void k_prep(
    const int* __restrict__ base_ids, const int* __restrict__ type_ids,
    const int* __restrict__ source_ids,
    const float* __restrict__ te, const float* __restrict__ se,
    const float* __restrict__ b2, const float* __restrict__ Wf,
    const float* __restrict__ bfv, const float* __restrict__ W2,
    int* __restrict__ cnt, int* __restrict__ idxArr,
    unsigned short* __restrict__ Cb,
    float* __restrict__ ABc, float* __restrict__ D2b) {
  __shared__ PrepSM sm;
  int b = blockIdx.x;
  int tid = threadIdx.x;
  int lane = tid & 63;
  int w = tid >> 6;

  if (b < 256) {
    // ---- scatter: per-block LDS aggregation, one atomic per (block,type) ----
    int e = (b << 8) + tid;
    int bt = base_ids[e];
    int pk = e | (type_ids[e] << 16) | (source_ids[e] << 20);
    unsigned long long lanebit = 1ull << lane;

    #pragma unroll 1
    for (int t = 0; t < T_N; ++t) {
      unsigned long long m = __ballot(bt == t);
      if (lane == 0) sm.s.sph[t][w] = __popcll(m);
    }
    __syncthreads();
    if (tid < T_N) {
      int c0 = sm.s.sph[tid][0], c1 = sm.s.sph[tid][1];
      int c2 = sm.s.sph[tid][2], c3 = sm.s.sph[tid][3];
      int tot = c0 + c1 + c2 + c3;
      int base = (tot > 0) ? atomicAdd(&cnt[tid << 4], tot) : 0;
      sm.s.sbase[tid] = base;
      sm.s.sph[tid][0] = 0;
      sm.s.sph[tid][1] = c0;
      sm.s.sph[tid][2] = c0 + c1;
      sm.s.sph[tid][3] = c0 + c1 + c2;
    }
    __syncthreads();
    #pragma unroll 1
    for (int t = 0; t < T_N; ++t) {
      unsigned long long m = __ballot(bt == t);
      if (bt == t) {
        int pos = sm.s.sbase[t] + sm.s.sph[t][w] + __popcll(m & (lanebit - 1ull));
        idxArr[t * E_N + pos] = pk;
      }
    }
  } else if (b < 321) {
    // ---- embed: each wave takes a k-chunk, lanes take 4 d-columns ----
    int bb = b - 256;
    int dg = lane << 2;
    f32x4 acc0 = {0.f, 0.f, 0.f, 0.f}, acc1 = {0.f, 0.f, 0.f, 0.f};
    if (bb < 56) {
      int ty = bb >> 2, sr = bb & 3;
      const float* src = (w < 2) ? (te + ty * 256) : (se + sr * 256 - 256);
      int kbase = w << 7;
      #pragma unroll 8
      for (int k = kbase; k < kbase + 128; k += 2) {
        f32x4 wv0 = *(const f32x4*)&Wf[((k + 0) << 8) + dg];
        f32x4 wv1 = *(const f32x4*)&Wf[((k + 1) << 8) + dg];
        float e0 = src[k], e1 = src[k + 1];
        acc0.x = fmaf(e0, wv0.x, acc0.x); acc0.y = fmaf(e0, wv0.y, acc0.y);
        acc0.z = fmaf(e0, wv0.z, acc0.z); acc0.w = fmaf(e0, wv0.w, acc0.w);
        acc1.x = fmaf(e1, wv1.x, acc1.x); acc1.y = fmaf(e1, wv1.y, acc1.y);
        acc1.z = fmaf(e1, wv1.z, acc1.z); acc1.w = fmaf(e1, wv1.w, acc1.w);
      }
    } else {
      int t = bb - 56;
      const float* bp = b2 + t * 256;
      int kbase = w << 6;
      #pragma unroll 8
      for (int k = kbase; k < kbase + 64; k += 2) {
        f32x4 wv0 = *(const f32x4*)&Wf[((512 + k + 0) << 8) + dg];
        f32x4 wv1 = *(const f32x4*)&Wf[((512 + k + 1) << 8) + dg];
        float e0 = bp[k], e1 = bp[k + 1];
        acc0.x = fmaf(e0, wv0.x, acc0.x); acc0.y = fmaf(e0, wv0.y, acc0.y);
        acc0.z = fmaf(e0, wv0.z, acc0.z); acc0.w = fmaf(e0, wv0.w, acc0.w);
        acc1.x = fmaf(e1, wv1.x, acc1.x); acc1.y = fmaf(e1, wv1.y, acc1.y);
        acc1.z = fmaf(e1, wv1.z, acc1.z); acc1.w = fmaf(e1, wv1.w, acc1.w);
      }
    }
    acc0 += acc1;
    *(f32x4*)&sm.e.partf[((w << 6) + lane) << 2] = acc0;
    __syncthreads();
    if (w == 0) {
      acc0 += *(const f32x4*)&sm.e.partf[((1 << 6) + lane) << 2];
      acc0 += *(const f32x4*)&sm.e.partf[((2 << 6) + lane) << 2];
      acc0 += *(const f32x4*)&sm.e.partf[((3 << 6) + lane) << 2];
      if (bb < 56) {
        *(f32x4*)&ABc[(bb << 8) + dg] = acc0;
      } else {
        f32x4 bv = *(const f32x4*)&bfv[dg];
        *(f32x4*)&D2b[((bb - 56) << 8) + dg] = acc0 + bv;
      }
    }
  } else {
    // ---- C[t] = W2[t] @ Wf2: per-wave k-quarter + LDS reduce ----
    int ci = b - 321;
    int t = ci >> 5;
    int j0 = (ci & 31) << 3;
    for (int i = tid; i < 2048; i += 256)
      sm.c.w2s[i >> 8][i & 255] =
          W2[(size_t)t * 65536 + (size_t)(j0 + (i >> 8)) * 256 + (i & 255)];
    __syncthreads();

    int dg = lane << 2;
    int kbase = w << 6;
    f32x4 acc[8];
    #pragma unroll
    for (int j = 0; j < 8; ++j) acc[j] = (f32x4){0.f, 0.f, 0.f, 0.f};
    #pragma unroll 2
    for (int k0 = 0; k0 < 64; k0 += 4) {
      f32x4 a[8];
      #pragma unroll
      for (int j = 0; j < 8; ++j) a[j] = *(const f32x4*)&sm.c.w2s[j][kbase + k0];
      #pragma unroll
      for (int kk = 0; kk < 4; ++kk) {
        f32x4 wv = *(const f32x4*)&Wf[((512 + kbase + k0 + kk) << 8) + dg];
        #pragma unroll
        for (int j = 0; j < 8; ++j) {
          float aj = a[j][kk];
          acc[j].x = fmaf(aj, wv.x, acc[j].x);
          acc[j].y = fmaf(aj, wv.y, acc[j].y);
          acc[j].z = fmaf(aj, wv.z, acc[j].z);
          acc[j].w = fmaf(aj, wv.w, acc[j].w);
        }
      }
    }
    if (w > 0) {
      #pragma unroll
      for (int j = 0; j < 8; ++j)
        *(f32x4*)&sm.c.partf[(((((w - 1) << 3) + j) << 6) + lane) << 2] = acc[j];
    }
    __syncthreads();
    if (w == 0) {
      #pragma unroll
      for (int p = 0; p < 3; ++p)
        #pragma unroll
        for (int j = 0; j < 8; ++j)
          acc[j] += *(const f32x4*)&sm.c.partf[((((p << 3) + j) << 6) + lane) << 2];
      unsigned short* CbT = Cb + (size_t)t * 65536;
      #pragma unroll
      for (int di = 0; di < 4; ++di) {
        ushort8 o;
        #pragma unroll
        for (int j = 0; j < 8; ++j) o[j] = f2bf(acc[j][di]);
        *(ushort8*)(CbT + ((size_t)((j0 >> 3) << 8) + dg + di) * 8) = o;
      }
    }
  }
}

// ============ K2: grouped GEMM via MFMA ============
__global__ __launch_bounds__(256, 4) void edge_gemm(
    const int* __restrict__ cnt, const int* __restrict__ idxArr,
    const float* __restrict__ params,
    const float* __restrict__ W1, const float* __restrict__ b1,
    const unsigned short* __restrict__ Cb, const float* __restrict__ ABc,
    const float* __restrict__ D2b, float* __restrict__ out) {
  int b = blockIdx.x;
  int t = -1, m0 = 0, n = 0;
  {
    int acc = 0;
    #pragma unroll
    for (int tt = 0; tt < T_N; ++tt) {
      int c = cnt[tt << 4];
      int nb = (c + 63) >> 6;
      if (t < 0 && b < acc + nb) { t = tt; m0 = (b - acc) << 6; n = c; }
      acc += nb;
    }
  }
  if (t < 0) return;

  __shared__ unsigned short hb[64 * 256];  // 32 KB; bf16 h (swizzled) then f32 rows
  __shared__ int eidx[64];                 // packed e|ty<<16|sr<<20
  __shared__ float4 xs[64];

  int tid = threadIdx.x;
  int lane = tid & 63;
  int w = tid >> 6;
  int l15 = lane & 15;
  int l4 = lane >> 4;

  const unsigned short* CbT = Cb + (size_t)t * 65536;

  // prefetch s=0 B-fragments (independent of phases A/B; overlaps their latency)
  bf16x8 bcur[4];
  #pragma unroll
  for (int nn = 0; nn < 4; ++nn) {
    U8 u;
    u.u = *(const ushort8*)(CbT + (size_t)((l4 << 8) + (w << 6) + (nn << 4) + l15) * 8);
    bcur[nn] = u.b;
  }

  if (tid < 64) {
    int m = m0 + tid;
    int mc = (m < n) ? m : (n - 1);
    int pk = idxArr[(size_t)t * E_N + mc];
    eidx[tid] = pk;
    int e = pk & 0xFFFF;
    float4 pr = *(const float4*)(params + (size_t)e * 4);
    float4 x;
    x.x = pr.x / SCALES_C[t][0];
    x.y = pr.y / SCALES_C[t][1];
    x.z = pr.z / SCALES_C[t][2];
    x.w = pr.w / SCALES_C[t][3];
    xs[tid] = x;
  }
  __syncthreads();

  // phase B: h = relu(x@W1+b1) -> bf16 packed pairs, XOR-swizzled LDS
  {
    int dp = tid & 127, mh = tid >> 7;
    int d0 = dp << 1;
    const float* W1t = W1 + t * 1024;
    float2 wq0 = *(const float2*)&W1t[d0];
    float2 wq1 = *(const float2*)&W1t[256 + d0];
    float2 wq2 = *(const float2*)&W1t[512 + d0];
    float2 wq3 = *(const float2*)&W1t[768 + d0];
    float2 bq  = *(const float2*)&b1[t * 256 + d0];
    int mb = mh << 5;
    #pragma unroll 4
    for (int i = 0; i < 32; ++i) {
      int m = mb + i;
      float4 x = xs[m];
      float h0 = fmaf(x.x, wq0.x, fmaf(x.y, wq1.x, fmaf(x.z, wq2.x, fmaf(x.w, wq3.x, bq.x))));
      float h1 = fmaf(x.x, wq0.y, fmaf(x.y, wq1.y, fmaf(x.z, wq2.y, fmaf(x.w, wq3.y, bq.y))));
      BF2 pk2;
      pk2.h[0] = (__bf16)fmaxf(h0, 0.f);
      pk2.h[1] = (__bf16)fmaxf(h1, 0.f);
      int off = (m << 9) + ((d0 << 1) ^ ((m & 7) << 4));
      *(unsigned int*)((char*)hb + off) = pk2.u;
    }
  }
  __syncthreads();

  f32x4 acc[4][4];
  #pragma unroll
  for (int i = 0; i < 4; ++i)
    #pragma unroll
    for (int j = 0; j < 4; ++j) acc[i][j] = (f32x4){0.f, 0.f, 0.f, 0.f};

  #pragma unroll 1
  for (int s = 0; s < 8; ++s) {
    // issue next step's B-frag loads before this step's MFMAs (depth-1 prefetch)
    bf16x8 bnext[4];
    int sn = (s + 1) & 7;
    #pragma unroll
    for (int nn = 0; nn < 4; ++nn) {
      int koct = (sn << 2) + l4;
      U8 u;
      u.u = *(const ushort8*)(CbT + (size_t)((koct << 8) + (w << 6) + (nn << 4) + l15) * 8);
      bnext[nn] = u.b;
    }
    #pragma unroll
    for (int mt = 0; mt < 4; ++mt) {
      int row = (mt << 4) + l15;
      int byte = (row << 9) + ((((s << 6) + (l4 << 4))) ^ ((row & 7) << 4));
      U8 a;
      a.u = *(const ushort8*)((const char*)hb + byte);
      #pragma unroll
      for (int nn = 0; nn < 4; ++nn)
        acc[mt][nn] = __builtin_amdgcn_mfma_f32_16x16x32_bf16(a.b, bcur[nn], acc[mt][nn], 0, 0, 0);
    }
    #pragma unroll
    for (int nn = 0; nn < 4; ++nn) bcur[nn] = bnext[nn];
  }

  // epilogue: transpose through LDS (hb dead), vectorized bias add + store
  float* fb = (float*)hb;
  const float* d2p = D2b + (t << 8);
  #pragma unroll
  for (int p = 0; p < 2; ++p) {
    __syncthreads();
    #pragma unroll
    for (int mh = 0; mh < 2; ++mh) {
      int mt = (p << 1) + mh;
      int lrb = (mh << 4) + (l4 << 2);
      #pragma unroll
      for (int nn = 0; nn < 4; ++nn) {
        int col = (w << 6) + (nn << 4) + l15;
        #pragma unroll
        for (int r = 0; r < 4; ++r) {
          int lr = lrb + r;
          fb[lr * 256 + (col ^ ((lr & 7) << 2))] = acc[mt][nn][r];
        }
      }
    }
    __syncthreads();
    int lr = tid >> 3;
    int c8 = tid & 7;
    int row_g = (p << 5) + lr;
    if (m0 + row_g < n) {
      int pk = eidx[row_g];
      int e = pk & 0xFFFF;
      int ty = (pk >> 16) & 15;
      int sr = (pk >> 20) & 3;
      const float* abp = ABc + (size_t)(((ty << 2) + sr) << 8);
      float* op = out + (size_t)e * 256;
      int sw = (lr & 7) << 2;
      #pragma unroll
      for (int v = 0; v < 8; ++v) {
        int col = (c8 << 2) + (v << 5);
        f32x4 vv = *(const f32x4*)&fb[lr * 256 + (col ^ sw)];
        f32x4 ab = *(const f32x4*)&abp[col];
        f32x4 d2 = *(const f32x4*)&d2p[col];
        f32x4 rr;
        rr.x = fmaxf(vv.x + ab.x + d2.x, 0.f);
        rr.y = fmaxf(vv.y + ab.y + d2.y, 0.f);
        rr.z = fmaxf(vv.z + ab.z + d2.z, 0.f);
        rr.w = fmaxf(vv.w + ab.w + d2.w, 0.f);
        *(f32x4*)&op[col] = rr;
      }
    }
  }
}

extern "C" void kernel_launch(void* const* d_in, const int* in_sizes, int n_in,
                              void* d_out, int out_size, void* d_ws, size_t ws_size,
                              hipStream_t stream) {
  const int*   type_ids   = (const int*)  d_in[0];
  const int*   source_ids = (const int*)  d_in[1];
  const int*   base_ids   = (const int*)  d_in[2];
  const float* params     = (const float*)d_in[3];
  const float* te         = (const float*)d_in[4];
  const float* se         = (const float*)d_in[5];
  const float* W1         = (const float*)d_in[6];
  const float* b1         = (const float*)d_in[7];
  const float* W2         = (const float*)d_in[8];
  const float* b2         = (const float*)d_in[9];
  const float* Wf         = (const float*)d_in[10];
  const float* bfv        = (const float*)d_in[11];
  float* out = (float*)d_out;

  if (ws_size < WS_NEED_BYTES) return;

  float* wsf = (float*)d_ws;
  unsigned short* Cb = (unsigned short*)(wsf + OFF_CB);
  float* ABc = wsf + OFF_ABC;
  float* D2b = wsf + OFF_D2;
  int*   cnt = (int*)(wsf + OFF_CNT);
  int*   idx = (int*)(wsf + OFF_IDX);

  hipMemsetAsync(cnt, 0, 160 * sizeof(int), stream);
  k_prep<<<609, 256, 0, stream>>>(base_ids, type_ids, source_ids, te, se, b2,
                                  Wf, bfv, W2, cnt, idx, Cb, ABc, D2b);
  edge_gemm<<<1033, 256, 0, stream>>>(cnt, idx, params, W1, b1, Cb, ABc, D2b, out);
}

// Round 8
// 57.454 us; speedup vs baseline: 1.0752x; 1.0752x over previous
//
#include <hip/hip_runtime.h>

#define E_N 65536
#define T_N 9

typedef __bf16 bf16x8 __attribute__((ext_vector_type(8)));
typedef float f32x4 __attribute__((ext_vector_type(4)));
typedef unsigned short ushort8 __attribute__((ext_vector_type(8)));
union U8 { ushort8 u; bf16x8 b; };
union BF2 { __bf16 h[2]; unsigned int u; };

// ---------------- ws layout (float offsets) ----------------
#define OFF_CB   0          // 9*256*256 ushort = 294912 floats (bf16 packed C)
#define OFF_ABC  294912     // 56*256 floats
#define OFF_D2   309248     // 9*256 floats
#define OFF_CNT  311552     // 9 counters padded to 16 ints each
#define OFF_IDX  311712     // 9*65536 ints
#define WS_NEED_BYTES ((size_t)(311712 + 589824) * 4)

__device__ __constant__ float SCALES_C[9][4] = {
  {1.f,    1e-6f, 1.f,  1.f},
  {1.f,    1e-6f, 1.f,  1.f},
  {1.f,    1.f,   1.f,  1.f},
  {1e3f,   1.f,   1.f,  1.f},
  {1e-12f, 1.f,   1.f,  1.f},
  {1e-9f,  1.f,   1.f,  1.f},
  {1.f,    1.f,   1.f,  1.f},
  {1e-3f,  1e-3f, 1.f,  1.f},
  {1.f,    1.f,   1e9f, 1.f},
};

__device__ inline unsigned short f2bf(float f) {
  unsigned int u = __float_as_uint(f);
  unsigned int r = (u + 0x7FFFu + ((u >> 16) & 1u)) >> 16;
  return (unsigned short)r;
}

// ============ K1: fused independent prep ============
// blocks [0,256): scatter (block-aggregated atomics, line-padded counters)
// blocks [256,321): embed/bias projections (k-split across waves + LDS reduce)
// blocks [321,609): C[t] = W2[t]@Wf2 (scalar W2 loads, per-wave k-quarter)
struct ScatSM { int sph[9][4]; int sbase[9]; };
struct EmbSM  { float partf[4 * 64 * 4]; };
struct CSM    { float partf[3 * 8 * 64 * 4]; };   // 24 KB
union PrepSM  { ScatSM s; EmbSM e; CSM c; };

__global__ __launch_bounds__(256) void k_prep(
    const int* __restrict__ base_ids, const int* __restrict__ type_ids,
    const int* __restrict__ source_ids,
    const float* __restrict__ te, const float* __restrict__ se,
    const float* __restrict__ b2, const float* __restrict__ Wf,
    const float* __restrict__ bfv, const float* __restrict__ W2,
    int* __restrict__ cnt, int* __restrict__ idxArr,
    unsigned short* __restrict__ Cb,
    float* __restrict__ ABc, float* __restrict__ D2b) {
  __shared__ PrepSM sm;
  int b = blockIdx.x;
  int tid = threadIdx.x;
  int lane = tid & 63;
  int w = tid >> 6;

  if (b < 256) {
    // ---- scatter: per-block LDS aggregation, one atomic per (block,type) ----
    int e = (b << 8) + tid;
    int bt = base_ids[e];
    int pk = e | (type_ids[e] << 16) | (source_ids[e] << 20);
    unsigned long long lanebit = 1ull << lane;

    #pragma unroll 1
    for (int t = 0; t < T_N; ++t) {
      unsigned long long m = __ballot(bt == t);
      if (lane == 0) sm.s.sph[t][w] = __popcll(m);
    }
    __syncthreads();
    if (tid < T_N) {
      int c0 = sm.s.sph[tid][0], c1 = sm.s.sph[tid][1];
      int c2 = sm.s.sph[tid][2], c3 = sm.s.sph[tid][3];
      int tot = c0 + c1 + c2 + c3;
      int base = (tot > 0) ? atomicAdd(&cnt[tid << 4], tot) : 0;
      sm.s.sbase[tid] = base;
      sm.s.sph[tid][0] = 0;
      sm.s.sph[tid][1] = c0;
      sm.s.sph[tid][2] = c0 + c1;
      sm.s.sph[tid][3] = c0 + c1 + c2;
    }
    __syncthreads();
    #pragma unroll 1
    for (int t = 0; t < T_N; ++t) {
      unsigned long long m = __ballot(bt == t);
      if (bt == t) {
        int pos = sm.s.sbase[t] + sm.s.sph[t][w] + __popcll(m & (lanebit - 1ull));
        idxArr[t * E_N + pos] = pk;
      }
    }
  } else if (b < 321) {
    // ---- embed: each wave takes a k-chunk, lanes take 4 d-columns ----
    int bb = b - 256;
    int dg = lane << 2;
    f32x4 acc0 = {0.f, 0.f, 0.f, 0.f}, acc1 = {0.f, 0.f, 0.f, 0.f};
    if (bb < 56) {
      int ty = bb >> 2, sr = bb & 3;
      const float* src = (w < 2) ? (te + ty * 256) : (se + sr * 256 - 256);
      int kbase = w << 7;
      #pragma unroll 8
      for (int k = kbase; k < kbase + 128; k += 2) {
        f32x4 wv0 = *(const f32x4*)&Wf[((k + 0) << 8) + dg];
        f32x4 wv1 = *(const f32x4*)&Wf[((k + 1) << 8) + dg];
        float e0 = src[k], e1 = src[k + 1];
        acc0.x = fmaf(e0, wv0.x, acc0.x); acc0.y = fmaf(e0, wv0.y, acc0.y);
        acc0.z = fmaf(e0, wv0.z, acc0.z); acc0.w = fmaf(e0, wv0.w, acc0.w);
        acc1.x = fmaf(e1, wv1.x, acc1.x); acc1.y = fmaf(e1, wv1.y, acc1.y);
        acc1.z = fmaf(e1, wv1.z, acc1.z); acc1.w = fmaf(e1, wv1.w, acc1.w);
      }
    } else {
      int t = bb - 56;
      const float* bp = b2 + t * 256;
      int kbase = w << 6;
      #pragma unroll 8
      for (int k = kbase; k < kbase + 64; k += 2) {
        f32x4 wv0 = *(const f32x4*)&Wf[((512 + k + 0) << 8) + dg];
        f32x4 wv1 = *(const f32x4*)&Wf[((512 + k + 1) << 8) + dg];
        float e0 = bp[k], e1 = bp[k + 1];
        acc0.x = fmaf(e0, wv0.x, acc0.x); acc0.y = fmaf(e0, wv0.y, acc0.y);
        acc0.z = fmaf(e0, wv0.z, acc0.z); acc0.w = fmaf(e0, wv0.w, acc0.w);
        acc1.x = fmaf(e1, wv1.x, acc1.x); acc1.y = fmaf(e1, wv1.y, acc1.y);
        acc1.z = fmaf(e1, wv1.z, acc1.z); acc1.w = fmaf(e1, wv1.w, acc1.w);
      }
    }
    acc0 += acc1;
    *(f32x4*)&sm.e.partf[((w << 6) + lane) << 2] = acc0;
    __syncthreads();
    if (w == 0) {
      acc0 += *(const f32x4*)&sm.e.partf[((1 << 6) + lane) << 2];
      acc0 += *(const f32x4*)&sm.e.partf[((2 << 6) + lane) << 2];
      acc0 += *(const f32x4*)&sm.e.partf[((3 << 6) + lane) << 2];
      if (bb < 56) {
        *(f32x4*)&ABc[(bb << 8) + dg] = acc0;
      } else {
        f32x4 bv = *(const f32x4*)&bfv[dg];
        *(f32x4*)&D2b[((bb - 56) << 8) + dg] = acc0 + bv;
      }
    }
  } else {
    // ---- C[t] = W2[t] @ Wf2: scalar (wave-uniform) W2 reads, per-wave k-quarter ----
    int ci = b - 321;
    int t = ci >> 5;
    int j0 = (ci & 31) << 3;
    const float* W2t = W2 + (size_t)t * 65536 + (size_t)j0 * 256;

    int dg = lane << 2;
    int kbase = w << 6;
    f32x4 acc[8];
    #pragma unroll
    for (int j = 0; j < 8; ++j) acc[j] = (f32x4){0.f, 0.f, 0.f, 0.f};
    #pragma unroll 2
    for (int k0 = 0; k0 < 64; k0 += 4) {
      f32x4 a[8];
      #pragma unroll
      for (int j = 0; j < 8; ++j) {
        int off = __builtin_amdgcn_readfirstlane((j << 8) + kbase + k0);
        a[j] = *(const f32x4*)(W2t + off);      // wave-uniform -> s_load_dwordx4
      }
      #pragma unroll
      for (int kk = 0; kk < 4; ++kk) {
        f32x4 wv = *(const f32x4*)&Wf[((512 + kbase + k0 + kk) << 8) + dg];
        #pragma unroll
        for (int j = 0; j < 8; ++j) {
          float aj = a[j][kk];
          acc[j].x = fmaf(aj, wv.x, acc[j].x);
          acc[j].y = fmaf(aj, wv.y, acc[j].y);
          acc[j].z = fmaf(aj, wv.z, acc[j].z);
          acc[j].w = fmaf(aj, wv.w, acc[j].w);
        }
      }
    }
    if (w > 0) {
      #pragma unroll
      for (int j = 0; j < 8; ++j)
        *(f32x4*)&sm.c.partf[(((((w - 1) << 3) + j) << 6) + lane) << 2] = acc[j];
    }
    __syncthreads();
    if (w == 0) {
      #pragma unroll
      for (int p = 0; p < 3; ++p)
        #pragma unroll
        for (int j = 0; j < 8; ++j)
          acc[j] += *(const f32x4*)&sm.c.partf[((((p << 3) + j) << 6) + lane) << 2];
      unsigned short* CbT = Cb + (size_t)t * 65536;
      #pragma unroll
      for (int di = 0; di < 4; ++di) {
        ushort8 o;
        #pragma unroll
        for (int j = 0; j < 8; ++j) o[j] = f2bf(acc[j][di]);
        *(ushort8*)(CbT + ((size_t)((j0 >> 3) << 8) + dg + di) * 8) = o;
      }
    }
  }
}

// ============ K2: grouped GEMM via MFMA, 128-edge tiles, 8 waves ============
__global__ __launch_bounds__(512, 4) void edge_gemm(
    const int* __restrict__ cnt, const int* __restrict__ idxArr,
    const float* __restrict__ params,
    const float* __restrict__ W1, const float* __restrict__ b1,
    const unsigned short* __restrict__ Cb, const float* __restrict__ ABc,
    const float* __restrict__ D2b, float* __restrict__ out) {
  int b = blockIdx.x;
  int t = -1, m0 = 0, n = 0;
  {
    int acc = 0;
    #pragma unroll
    for (int tt = 0; tt < T_N; ++tt) {
      int c = cnt[tt << 4];
      int nb = (c + 127) >> 7;
      if (t < 0 && b < acc + nb) { t = tt; m0 = (b - acc) << 7; n = c; }
      acc += nb;
    }
  }
  if (t < 0) return;

  __shared__ unsigned short hb[128 * 256];  // 64 KB; bf16 h (swizzled), f32 in epilogue
  __shared__ int eidx[128];                 // packed e|ty<<16|sr<<20
  __shared__ float4 xs[128];

  int tid = threadIdx.x;
  int lane = tid & 63;
  int w = tid >> 6;          // 0..7
  int l15 = lane & 15;
  int l4 = lane >> 4;
  int wm = w >> 2;           // row half (0..1)
  int wn = w & 3;            // col quarter (0..3)

  if (tid < 128) {
    int m = m0 + tid;
    int mc = (m < n) ? m : (n - 1);
    int pk = idxArr[(size_t)t * E_N + mc];
    eidx[tid] = pk;
    int e = pk & 0xFFFF;
    float4 pr = *(const float4*)(params + (size_t)e * 4);
    float4 x;
    x.x = pr.x / SCALES_C[t][0];
    x.y = pr.y / SCALES_C[t][1];
    x.z = pr.z / SCALES_C[t][2];
    x.w = pr.w / SCALES_C[t][3];
    xs[tid] = x;
  }
  __syncthreads();

  // phase B: h = relu(x@W1+b1) -> bf16 packed pairs, XOR-swizzled LDS
  {
    int dp = tid & 127, mh = tid >> 7;   // mh 0..3 -> 32-row band
    int d0 = dp << 1;
    const float* W1t = W1 + t * 1024;
    float2 wq0 = *(const float2*)&W1t[d0];
    float2 wq1 = *(const float2*)&W1t[256 + d0];
    float2 wq2 = *(const float2*)&W1t[512 + d0];
    float2 wq3 = *(const float2*)&W1t[768 + d0];
    float2 bq  = *(const float2*)&b1[t * 256 + d0];
    int mb = mh << 5;
    #pragma unroll 4
    for (int i = 0; i < 32; ++i) {
      int m = mb + i;
      float4 x = xs[m];
      float h0 = fmaf(x.x, wq0.x, fmaf(x.y, wq1.x, fmaf(x.z, wq2.x, fmaf(x.w, wq3.x, bq.x))));
      float h1 = fmaf(x.x, wq0.y, fmaf(x.y, wq1.y, fmaf(x.z, wq2.y, fmaf(x.w, wq3.y, bq.y))));
      BF2 pk2;
      pk2.h[0] = (__bf16)fmaxf(h0, 0.f);
      pk2.h[1] = (__bf16)fmaxf(h1, 0.f);
      int off = (m << 9) + ((d0 << 1) ^ ((m & 7) << 4));
      *(unsigned int*)((char*)hb + off) = pk2.u;
    }
  }
  __syncthreads();

  f32x4 acc[4][4];
  #pragma unroll
  for (int i = 0; i < 4; ++i)
    #pragma unroll
    for (int j = 0; j < 4; ++j) acc[i][j] = (f32x4){0.f, 0.f, 0.f, 0.f};

  const unsigned short* CbT = Cb + (size_t)t * 65536;

  #pragma unroll 1
  for (int s = 0; s < 8; ++s) {
    bf16x8 bfr[4];
    #pragma unroll
    for (int nn = 0; nn < 4; ++nn) {
      int koct = (s << 2) + l4;
      int d = (wn << 6) + (nn << 4) + l15;
      U8 u;
      u.u = *(const ushort8*)(CbT + (size_t)((koct << 8) + d) * 8);
      bfr[nn] = u.b;
    }
    __builtin_amdgcn_s_setprio(1);
    #pragma unroll
    for (int mt = 0; mt < 4; ++mt) {
      int row = (wm << 6) + (mt << 4) + l15;
      int byte = (row << 9) + ((((s << 6) + (l4 << 4))) ^ ((row & 7) << 4));
      U8 a;
      a.u = *(const ushort8*)((const char*)hb + byte);
      #pragma unroll
      for (int nn = 0; nn < 4; ++nn)
        acc[mt][nn] = __builtin_amdgcn_mfma_f32_16x16x32_bf16(a.b, bfr[nn], acc[mt][nn], 0, 0, 0);
    }
    __builtin_amdgcn_s_setprio(0);
  }

  // epilogue: transpose through LDS (hb dead), 2 passes of 64 rows
  float* fb = (float*)hb;                  // [64][256] f32 per pass = 64 KB
  const float* d2p = D2b + (t << 8);
  #pragma unroll
  for (int p = 0; p < 2; ++p) {
    __syncthreads();
    if (wm == p) {
      #pragma unroll
      for (int mt = 0; mt < 4; ++mt) {
        #pragma unroll
        for (int nn = 0; nn < 4; ++nn) {
          int col = (wn << 6) + (nn << 4) + l15;
          #pragma unroll
          for (int r = 0; r < 4; ++r) {
            int lr = (mt << 4) + (l4 << 2) + r;    // 0..63
            fb[lr * 256 + (col ^ ((lr & 7) << 2))] = acc[mt][nn][r];
          }
        }
      }
    }
    __syncthreads();
    int lr = tid >> 3;                     // 0..63
    int c8 = tid & 7;
    int row_g = (p << 6) + lr;
    if (m0 + row_g < n) {
      int pk = eidx[row_g];
      int e = pk & 0xFFFF;
      int ty = (pk >> 16) & 15;
      int sr = (pk >> 20) & 3;
      const float* abp = ABc + (size_t)(((ty << 2) + sr) << 8);
      float* op = out + (size_t)e * 256;
      int sw = (lr & 7) << 2;
      #pragma unroll
      for (int v = 0; v < 8; ++v) {
        int col = (c8 << 2) + (v << 5);
        f32x4 vv = *(const f32x4*)&fb[lr * 256 + (col ^ sw)];
        f32x4 ab = *(const f32x4*)&abp[col];
        f32x4 d2 = *(const f32x4*)&d2p[col];
        f32x4 rr;
        rr.x = fmaxf(vv.x + ab.x + d2.x, 0.f);
        rr.y = fmaxf(vv.y + ab.y + d2.y, 0.f);
        rr.z = fmaxf(vv.z + ab.z + d2.z, 0.f);
        rr.w = fmaxf(vv.w + ab.w + d2.w, 0.f);
        *(f32x4*)&op[col] = rr;
      }
    }
  }
}

extern "C" void kernel_launch(void* const* d_in, const int* in_sizes, int n_in,
                              void* d_out, int out_size, void* d_ws, size_t ws_size,
                              hipStream_t stream) {
  const int*   type_ids   = (const int*)  d_in[0];
  const int*   source_ids = (const int*)  d_in[1];
  const int*   base_ids   = (const int*)  d_in[2];
  const float* params     = (const float*)d_in[3];
  const float* te         = (const float*)d_in[4];
  const float* se         = (const float*)d_in[5];
  const float* W1         = (const float*)d_in[6];
  const float* b1         = (const float*)d_in[7];
  const float* W2         = (const float*)d_in[8];
  const float* b2         = (const float*)d_in[9];
  const float* Wf         = (const float*)d_in[10];
  const float* bfv        = (const float*)d_in[11];
  float* out = (float*)d_out;

  if (ws_size < WS_NEED_BYTES) return;

  float* wsf = (float*)d_ws;
  unsigned short* Cb = (unsigned short*)(wsf + OFF_CB);
  float* ABc = wsf + OFF_ABC;
  float* D2b = wsf + OFF_D2;
  int*   cnt = (int*)(wsf + OFF_CNT);
  int*   idx = (int*)(wsf + OFF_IDX);

  hipMemsetAsync(cnt, 0, 160 * sizeof(int), stream);
  k_prep<<<609, 256, 0, stream>>>(base_ids, type_ids, source_ids, te, se, b2,
                                  Wf, bfv, W2, cnt, idx, Cb, ABc, D2b);
  edge_gemm<<<521, 512, 0, stream>>>(cnt, idx, params, W1, b1, Cb, ABc, D2b, out);
}

// Round 9
// 55.947 us; speedup vs baseline: 1.1042x; 1.0269x over previous
//
#include <hip/hip_runtime.h>

#define E_N 65536
#define T_N 9

typedef __bf16 bf16x8 __attribute__((ext_vector_type(8)));
typedef float f32x4 __attribute__((ext_vector_type(4)));
typedef unsigned short ushort8 __attribute__((ext_vector_type(8)));
union U8 { ushort8 u; bf16x8 b; };
union BF2 { __bf16 h[2]; unsigned int u; };

// ---------------- ws layout (float offsets) ----------------
#define OFF_CB   0          // 9*256*256 ushort = 294912 floats (bf16 packed C)
#define OFF_ABC  294912     // 56*256 floats
#define OFF_D2   309248     // 9*256 floats
#define OFF_CNT  311552     // 9 counters padded to 16 ints each
#define OFF_IDX  311712     // 9*65536 ints
#define WS_NEED_BYTES ((size_t)(311712 + 589824) * 4)

__device__ __constant__ float SCALES_C[9][4] = {
  {1.f,    1e-6f, 1.f,  1.f},
  {1.f,    1e-6f, 1.f,  1.f},
  {1.f,    1.f,   1.f,  1.f},
  {1e3f,   1.f,   1.f,  1.f},
  {1e-12f, 1.f,   1.f,  1.f},
  {1e-9f,  1.f,   1.f,  1.f},
  {1.f,    1.f,   1.f,  1.f},
  {1e-3f,  1e-3f, 1.f,  1.f},
  {1.f,    1.f,   1e9f, 1.f},
};

__device__ inline unsigned short f2bf(float f) {
  unsigned int u = __float_as_uint(f);
  unsigned int r = (u + 0x7FFFu + ((u >> 16) & 1u)) >> 16;
  return (unsigned short)r;
}

// ============ K1: fused independent prep ============
// blocks [0,256): scatter (block-aggregated atomics, line-padded counters)
// blocks [256,321): embed/bias projections (k-split across waves + LDS reduce)
// blocks [321,609): C[t] = W2[t]@Wf2 (scalar W2 loads, per-wave k-quarter,
//                   all-wave parallel reduce tail)
struct ScatSM { int sph[9][4]; int sbase[9]; };
struct EmbSM  { float partf[4 * 64 * 4]; };
struct CSM    { float partf[4 * 8 * 64 * 4]; };   // 32 KB: [q][j][lane] f32x4
union PrepSM  { ScatSM s; EmbSM e; CSM c; };

__global__ __launch_bounds__(256) void k_prep(
    const int* __restrict__ base_ids, const int* __restrict__ type_ids,
    const int* __restrict__ source_ids,
    const float* __restrict__ te, const float* __restrict__ se,
    const float* __restrict__ b2, const float* __restrict__ Wf,
    const float* __restrict__ bfv, const float* __restrict__ W2,
    int* __restrict__ cnt, int* __restrict__ idxArr,
    unsigned short* __restrict__ Cb,
    float* __restrict__ ABc, float* __restrict__ D2b) {
  __shared__ PrepSM sm;
  int b = blockIdx.x;
  int tid = threadIdx.x;
  int lane = tid & 63;
  int w = tid >> 6;

  if (b < 256) {
    // ---- scatter: per-block LDS aggregation, one atomic per (block,type) ----
    int e = (b << 8) + tid;
    int bt = base_ids[e];
    int pk = e | (type_ids[e] << 16) | (source_ids[e] << 20);
    unsigned long long lanebit = 1ull << lane;

    #pragma unroll 1
    for (int t = 0; t < T_N; ++t) {
      unsigned long long m = __ballot(bt == t);
      if (lane == 0) sm.s.sph[t][w] = __popcll(m);
    }
    __syncthreads();
    if (tid < T_N) {
      int c0 = sm.s.sph[tid][0], c1 = sm.s.sph[tid][1];
      int c2 = sm.s.sph[tid][2], c3 = sm.s.sph[tid][3];
      int tot = c0 + c1 + c2 + c3;
      int base = (tot > 0) ? atomicAdd(&cnt[tid << 4], tot) : 0;
      sm.s.sbase[tid] = base;
      sm.s.sph[tid][0] = 0;
      sm.s.sph[tid][1] = c0;
      sm.s.sph[tid][2] = c0 + c1;
      sm.s.sph[tid][3] = c0 + c1 + c2;
    }
    __syncthreads();
    #pragma unroll 1
    for (int t = 0; t < T_N; ++t) {
      unsigned long long m = __ballot(bt == t);
      if (bt == t) {
        int pos = sm.s.sbase[t] + sm.s.sph[t][w] + __popcll(m & (lanebit - 1ull));
        idxArr[t * E_N + pos] = pk;
      }
    }
  } else if (b < 321) {
    // ---- embed: each wave takes a k-chunk, lanes take 4 d-columns ----
    int bb = b - 256;
    int dg = lane << 2;
    f32x4 acc0 = {0.f, 0.f, 0.f, 0.f}, acc1 = {0.f, 0.f, 0.f, 0.f};
    if (bb < 56) {
      int ty = bb >> 2, sr = bb & 3;
      const float* src = (w < 2) ? (te + ty * 256) : (se + sr * 256 - 256);
      int kbase = w << 7;
      #pragma unroll 8
      for (int k = kbase; k < kbase + 128; k += 2) {
        f32x4 wv0 = *(const f32x4*)&Wf[((k + 0) << 8) + dg];
        f32x4 wv1 = *(const f32x4*)&Wf[((k + 1) << 8) + dg];
        float e0 = src[k], e1 = src[k + 1];
        acc0.x = fmaf(e0, wv0.x, acc0.x); acc0.y = fmaf(e0, wv0.y, acc0.y);
        acc0.z = fmaf(e0, wv0.z, acc0.z); acc0.w = fmaf(e0, wv0.w, acc0.w);
        acc1.x = fmaf(e1, wv1.x, acc1.x); acc1.y = fmaf(e1, wv1.y, acc1.y);
        acc1.z = fmaf(e1, wv1.z, acc1.z); acc1.w = fmaf(e1, wv1.w, acc1.w);
      }
    } else {
      int t = bb - 56;
      const float* bp = b2 + t * 256;
      int kbase = w << 6;
      #pragma unroll 8
      for (int k = kbase; k < kbase + 64; k += 2) {
        f32x4 wv0 = *(const f32x4*)&Wf[((512 + k + 0) << 8) + dg];
        f32x4 wv1 = *(const f32x4*)&Wf[((512 + k + 1) << 8) + dg];
        float e0 = bp[k], e1 = bp[k + 1];
        acc0.x = fmaf(e0, wv0.x, acc0.x); acc0.y = fmaf(e0, wv0.y, acc0.y);
        acc0.z = fmaf(e0, wv0.z, acc0.z); acc0.w = fmaf(e0, wv0.w, acc0.w);
        acc1.x = fmaf(e1, wv1.x, acc1.x); acc1.y = fmaf(e1, wv1.y, acc1.y);
        acc1.z = fmaf(e1, wv1.z, acc1.z); acc1.w = fmaf(e1, wv1.w, acc1.w);
      }
    }
    acc0 += acc1;
    *(f32x4*)&sm.e.partf[((w << 6) + lane) << 2] = acc0;
    __syncthreads();
    if (w == 0) {
      acc0 += *(const f32x4*)&sm.e.partf[((1 << 6) + lane) << 2];
      acc0 += *(const f32x4*)&sm.e.partf[((2 << 6) + lane) << 2];
      acc0 += *(const f32x4*)&sm.e.partf[((3 << 6) + lane) << 2];
      if (bb < 56) {
        *(f32x4*)&ABc[(bb << 8) + dg] = acc0;
      } else {
        f32x4 bv = *(const f32x4*)&bfv[dg];
        *(f32x4*)&D2b[((bb - 56) << 8) + dg] = acc0 + bv;
      }
    }
  } else {
    // ---- C[t] = W2[t] @ Wf2: scalar (wave-uniform) W2 reads, per-wave k-quarter ----
    int ci = b - 321;
    int t = ci >> 5;
    int j0 = (ci & 31) << 3;
    const float* W2t = W2 + (size_t)t * 65536 + (size_t)j0 * 256;

    int dg = lane << 2;
    int kbase = w << 6;
    f32x4 acc[8];
    #pragma unroll
    for (int j = 0; j < 8; ++j) acc[j] = (f32x4){0.f, 0.f, 0.f, 0.f};
    #pragma unroll 2
    for (int k0 = 0; k0 < 64; k0 += 4) {
      f32x4 a[8];
      #pragma unroll
      for (int j = 0; j < 8; ++j) {
        int off = __builtin_amdgcn_readfirstlane((j << 8) + kbase + k0);
        a[j] = *(const f32x4*)(W2t + off);      // wave-uniform -> s_load_dwordx4
      }
      #pragma unroll
      for (int kk = 0; kk < 4; ++kk) {
        f32x4 wv = *(const f32x4*)&Wf[((512 + kbase + k0 + kk) << 8) + dg];
        #pragma unroll
        for (int j = 0; j < 8; ++j) {
          float aj = a[j][kk];
          acc[j].x = fmaf(aj, wv.x, acc[j].x);
          acc[j].y = fmaf(aj, wv.y, acc[j].y);
          acc[j].z = fmaf(aj, wv.z, acc[j].z);
          acc[j].w = fmaf(aj, wv.w, acc[j].w);
        }
      }
    }
    // all 4 waves write partials: partf[q=w][j][lane]
    #pragma unroll
    for (int j = 0; j < 8; ++j)
      *(f32x4*)&sm.c.partf[((((w << 3) + j) << 6) + lane) << 2] = acc[j];
    __syncthreads();
    // wave w reduces j-rows {2w, 2w+1} (sum order q0+q1+q2+q3, bit-identical)
    {
      int jl0 = w << 1;
      f32x4 s[2];
      #pragma unroll
      for (int jj = 0; jj < 2; ++jj) {
        int j = jl0 + jj;
        f32x4 a2 = *(const f32x4*)&sm.c.partf[((j << 6) + lane) << 2];
        #pragma unroll
        for (int q = 1; q < 4; ++q)
          a2 += *(const f32x4*)&sm.c.partf[((((q << 3) + j) << 6) + lane) << 2];
        s[jj] = a2;
      }
      unsigned short* CbT = Cb + (size_t)t * 65536;
      #pragma unroll
      for (int di = 0; di < 4; ++di) {
        unsigned int pk2 = (unsigned int)f2bf(s[0][di]) |
                           ((unsigned int)f2bf(s[1][di]) << 16);
        *(unsigned int*)&CbT[((size_t)((j0 >> 3) << 8) + dg + di) * 8 + jl0] = pk2;
      }
    }
  }
}

// ============ K2: grouped GEMM via MFMA, 128-edge tiles, 8 waves ============
__global__ __launch_bounds__(512, 4) void edge_gemm(
    const int* __restrict__ cnt, const int* __restrict__ idxArr,
    const float* __restrict__ params,
    const float* __restrict__ W1, const float* __restrict__ b1,
    const unsigned short* __restrict__ Cb, const float* __restrict__ ABc,
    const float* __restrict__ D2b, float* __restrict__ out) {
  int b = blockIdx.x;
  int t = -1, m0 = 0, n = 0;
  {
    int acc = 0;
    #pragma unroll
    for (int tt = 0; tt < T_N; ++tt) {
      int c = cnt[tt << 4];
      int nb = (c + 127) >> 7;
      if (t < 0 && b < acc + nb) { t = tt; m0 = (b - acc) << 7; n = c; }
      acc += nb;
    }
  }
  if (t < 0) return;

  __shared__ unsigned short hb[128 * 256];  // 64 KB; bf16 h (swizzled), f32 in epilogue
  __shared__ int eidx[128];                 // packed e|ty<<16|sr<<20
  __shared__ float4 xs[128];

  int tid = threadIdx.x;
  int lane = tid & 63;
  int w = tid >> 6;          // 0..7
  int l15 = lane & 15;
  int l4 = lane >> 4;
  int wm = w >> 2;           // row half (0..1)
  int wn = w & 3;            // col quarter (0..3)

  if (tid < 128) {
    int m = m0 + tid;
    int mc = (m < n) ? m : (n - 1);
    int pk = idxArr[(size_t)t * E_N + mc];
    eidx[tid] = pk;
    int e = pk & 0xFFFF;
    float4 pr = *(const float4*)(params + (size_t)e * 4);
    float4 x;
    x.x = pr.x / SCALES_C[t][0];
    x.y = pr.y / SCALES_C[t][1];
    x.z = pr.z / SCALES_C[t][2];
    x.w = pr.w / SCALES_C[t][3];
    xs[tid] = x;
  }
  __syncthreads();

  // phase B: h = relu(x@W1+b1) -> bf16 packed pairs, XOR-swizzled LDS
  {
    int dp = tid & 127, mh = tid >> 7;   // mh 0..3 -> 32-row band
    int d0 = dp << 1;
    const float* W1t = W1 + t * 1024;
    float2 wq0 = *(const float2*)&W1t[d0];
    float2 wq1 = *(const float2*)&W1t[256 + d0];
    float2 wq2 = *(const float2*)&W1t[512 + d0];
    float2 wq3 = *(const float2*)&W1t[768 + d0];
    float2 bq  = *(const float2*)&b1[t * 256 + d0];
    int mb = mh << 5;
    #pragma unroll 4
    for (int i = 0; i < 32; ++i) {
      int m = mb + i;
      float4 x = xs[m];
      float h0 = fmaf(x.x, wq0.x, fmaf(x.y, wq1.x, fmaf(x.z, wq2.x, fmaf(x.w, wq3.x, bq.x))));
      float h1 = fmaf(x.x, wq0.y, fmaf(x.y, wq1.y, fmaf(x.z, wq2.y, fmaf(x.w, wq3.y, bq.y))));
      BF2 pk2;
      pk2.h[0] = (__bf16)fmaxf(h0, 0.f);
      pk2.h[1] = (__bf16)fmaxf(h1, 0.f);
      int off = (m << 9) + ((d0 << 1) ^ ((m & 7) << 4));
      *(unsigned int*)((char*)hb + off) = pk2.u;
    }
  }
  __syncthreads();

  f32x4 acc[4][4];
  #pragma unroll
  for (int i = 0; i < 4; ++i)
    #pragma unroll
    for (int j = 0; j < 4; ++j) acc[i][j] = (f32x4){0.f, 0.f, 0.f, 0.f};

  const unsigned short* CbT = Cb + (size_t)t * 65536;

  #pragma unroll 2
  for (int s = 0; s < 8; ++s) {
    bf16x8 bfr[4];
    #pragma unroll
    for (int nn = 0; nn < 4; ++nn) {
      int koct = (s << 2) + l4;
      int d = (wn << 6) + (nn << 4) + l15;
      U8 u;
      u.u = *(const ushort8*)(CbT + (size_t)((koct << 8) + d) * 8);
      bfr[nn] = u.b;
    }
    __builtin_amdgcn_s_setprio(1);
    #pragma unroll
    for (int mt = 0; mt < 4; ++mt) {
      int row = (wm << 6) + (mt << 4) + l15;
      int byte = (row << 9) + ((((s << 6) + (l4 << 4))) ^ ((row & 7) << 4));
      U8 a;
      a.u = *(const ushort8*)((const char*)hb + byte);
      #pragma unroll
      for (int nn = 0; nn < 4; ++nn)
        acc[mt][nn] = __builtin_amdgcn_mfma_f32_16x16x32_bf16(a.b, bfr[nn], acc[mt][nn], 0, 0, 0);
    }
    __builtin_amdgcn_s_setprio(0);
  }

  // epilogue: transpose through LDS (hb dead), 2 passes of 64 rows, nt stores
  float* fb = (float*)hb;                  // [64][256] f32 per pass = 64 KB
  const float* d2p = D2b + (t << 8);
  #pragma unroll
  for (int p = 0; p < 2; ++p) {
    __syncthreads();
    if (wm == p) {
      #pragma unroll
      for (int mt = 0; mt < 4; ++mt) {
        #pragma unroll
        for (int nn = 0; nn < 4; ++nn) {
          int col = (wn << 6) + (nn << 4) + l15;
          #pragma unroll
          for (int r = 0; r < 4; ++r) {
            int lr = (mt << 4) + (l4 << 2) + r;    // 0..63
            fb[lr * 256 + (col ^ ((lr & 7) << 2))] = acc[mt][nn][r];
          }
        }
      }
    }
    __syncthreads();
    int lr = tid >> 3;                     // 0..63
    int c8 = tid & 7;
    int row_g = (p << 6) + lr;
    if (m0 + row_g < n) {
      int pk = eidx[row_g];
      int e = pk & 0xFFFF;
      int ty = (pk >> 16) & 15;
      int sr = (pk >> 20) & 3;
      const float* abp = ABc + (size_t)(((ty << 2) + sr) << 8);
      float* op = out + (size_t)e * 256;
      int sw = (lr & 7) << 2;
      #pragma unroll
      for (int v = 0; v < 8; ++v) {
        int col = (c8 << 2) + (v << 5);
        f32x4 vv = *(const f32x4*)&fb[lr * 256 + (col ^ sw)];
        f32x4 ab = *(const f32x4*)&abp[col];
        f32x4 d2 = *(const f32x4*)&d2p[col];
        f32x4 rr;
        rr.x = fmaxf(vv.x + ab.x + d2.x, 0.f);
        rr.y = fmaxf(vv.y + ab.y + d2.y, 0.f);
        rr.z = fmaxf(vv.z + ab.z + d2.z, 0.f);
        rr.w = fmaxf(vv.w + ab.w + d2.w, 0.f);
        __builtin_nontemporal_store(rr, (f32x4*)&op[col]);
      }
    }
  }
}

extern "C" void kernel_launch(void* const* d_in, const int* in_sizes, int n_in,
                              void* d_out, int out_size, void* d_ws, size_t ws_size,
                              hipStream_t stream) {
  const int*   type_ids   = (const int*)  d_in[0];
  const int*   source_ids = (const int*)  d_in[1];
  const int*   base_ids   = (const int*)  d_in[2];
  const float* params     = (const float*)d_in[3];
  const float* te         = (const float*)d_in[4];
  const float* se         = (const float*)d_in[5];
  const float* W1         = (const float*)d_in[6];
  const float* b1         = (const float*)d_in[7];
  const float* W2         = (const float*)d_in[8];
  const float* b2         = (const float*)d_in[9];
  const float* Wf         = (const float*)d_in[10];
  const float* bfv        = (const float*)d_in[11];
  float* out = (float*)d_out;

  if (ws_size < WS_NEED_BYTES) return;

  float* wsf = (float*)d_ws;
  unsigned short* Cb = (unsigned short*)(wsf + OFF_CB);
  float* ABc = wsf + OFF_ABC;
  float* D2b = wsf + OFF_D2;
  int*   cnt = (int*)(wsf + OFF_CNT);
  int*   idx = (int*)(wsf + OFF_IDX);

  hipMemsetAsync(cnt, 0, 160 * sizeof(int), stream);
  k_prep<<<609, 256, 0, stream>>>(base_ids, type_ids, source_ids, te, se, b2,
                                  Wf, bfv, W2, cnt, idx, Cb, ABc, D2b);
  edge_gemm<<<521, 512, 0, stream>>>(cnt, idx, params, W1, b1, Cb, ABc, D2b, out);
}